// Round 2
// baseline (600.604 us; speedup 1.0000x reference)
//
#include <hip/hip_runtime.h>

// Depthwise "true" 2D convolution: 3072 independent 128x128 fp32 images,
// each with its own 15x15 fp32 kernel, same-padding 7.
// y[i,j] = sum_{a,b} x[i+7-a, j+7-b] * k[a,b]   (zero outside [0,128))
//
// R3 -> R4 change: ty-separating swizzle keys on top of the de-interleaved
// slot layout. R3 (key=row&7) removed within-ty conflicts but gave rows 8
// apart (ty0/ty2, ty1/ty3 in a wave) IDENTICAL keys -> same physical slots
// for same tx. Residual SQ_LDS_BANK_CONFLICT=1.12e8 (~2-way on every read)
// implies LDS phases stripe lanes across the four 16-lane ty rows, so those
// same-slot lanes land in one phase. New key = 2*((row>>2)&3): the 4 ty
// groups in any single instruction get 4 distinct keys {0,2,4,6} (permuted)
// whose pairwise XORs are even; a striped lane pair {t,t+1} has odd t^(t+1),
// so {t,t+1} XOR {keys} yields 8 distinct bank clusters. Contiguous-lane
// groupings remain conflict-free (any fixed key is a bijection mod 8).

namespace {

constexpr int P      = 128;           // patch size
constexpr int K      = 15;            // kernel size
constexpr int HALF   = 64;            // output rows per block
constexpr int LROWS  = HALF + K - 1;  // 78 staged rows
constexpr int LM     = 36;            // logical float4 slots per row (144 floats)
constexpr int LWP    = 160;           // physical row width in floats (40 slots;
                                      // dein image [0,17]u[20,37], ^{0,2,4,6} stays <40)
constexpr int NT     = 256;

__device__ __forceinline__ int dein(int m) {
    // de-interleave even/odd logical float4 slots
    return (m >> 1) + (m & 1) * 20;
}

__device__ __forceinline__ int rowkey(int row) {
    // 4 distinct keys for rows spaced 4 apart, pairwise-XOR even
    return (row >> 1) & 6;            // == 2*((row>>2)&3)
}

__global__ __launch_bounds__(NT, 3)
void dwconv_kernel(const float* __restrict__ patches,
                   const float* __restrict__ kernels,
                   float* __restrict__ out)
{
    __shared__ float xs[LROWS * LWP];  // 49920 B, de-interleaved + keyed layout
    __shared__ float ks[K * 16];       // kernel rows padded to 16 floats

    const int tid   = threadIdx.x;
    const int n     = blockIdx.x >> 1;        // image index 0..3071
    const int halfb = blockIdx.x & 1;
    const int ibase = halfb * HALF;           // first output row of this block

    const float* img  = patches + (size_t)n * (P * P);
    const float* kern = kernels + (size_t)n * (K * K);

    // ---- stage kernel: 15 rows padded to 16 floats, col 15 zeroed ----
    if (tid < K * 16) {
        const int a = tid >> 4;
        const int b = tid & 15;
        ks[tid] = (b < K) ? kern[a * K + b] : 0.0f;
    }

    // ---- stage input strip rows [ibase-7, ibase+70] with zero halo ----
    // 78 rows * 36 float4 chunks; logical col of chunk m is 4m-8 (8-col halo)
    for (int idx = tid; idx < LROWS * LM; idx += NT) {
        const int row = idx / LM;
        const int m   = idx - row * LM;
        const int r   = ibase - 7 + row;       // global input row
        const int g0  = m * 4 - 8;             // global col of first float
        float4 v = make_float4(0.f, 0.f, 0.f, 0.f);
        if ((unsigned)r < (unsigned)P) {
            if (g0 >= 0 && g0 + 3 < P) {
                v = *reinterpret_cast<const float4*>(img + r * P + g0);
            } else {
                float t0 = 0.f, t1 = 0.f, t2 = 0.f, t3 = 0.f;
                const float* rp = img + r * P;
                if ((unsigned)(g0 + 0) < (unsigned)P) t0 = rp[g0 + 0];
                if ((unsigned)(g0 + 1) < (unsigned)P) t1 = rp[g0 + 1];
                if ((unsigned)(g0 + 2) < (unsigned)P) t2 = rp[g0 + 2];
                if ((unsigned)(g0 + 3) < (unsigned)P) t3 = rp[g0 + 3];
                v = make_float4(t0, t1, t2, t3);
            }
        }
        const int phys = dein(m) ^ rowkey(row);
        *reinterpret_cast<float4*>(xs + row * LWP + 4 * phys) = v;
    }
    __syncthreads();

    // ---- per-thread 4x8 output tile ----
    const int ty = tid >> 4;       // 0..15
    const int tx = tid & 15;       // 0..15
    const int i0 = ty * 4;         // local output row base (0..60)
    const int j0 = tx * 8;         // output col base (0..120)

    // logical slots needed per row: m = 2*tx + q, q=0..5
    // dein(2*tx+q) = tx + (q>>1) + (q&1)*20  -> per-thread constants:
    const int dbase[6] = { tx + 0, tx + 20, tx + 1, tx + 21, tx + 2, tx + 22 };

    float acc[4][8];
    #pragma unroll
    for (int rr = 0; rr < 4; ++rr)
        #pragma unroll
        for (int s = 0; s < 8; ++s)
            acc[rr][s] = 0.0f;

    #pragma unroll 1
    for (int a = 0; a < K; ++a) {
        // broadcast-load kernel row a (16 floats, last is 0)
        float kv[16];
        #pragma unroll
        for (int q = 0; q < 4; ++q) {
            const float4 kk = *reinterpret_cast<const float4*>(ks + a * 16 + q * 4);
            kv[q * 4 + 0] = kk.x;
            kv[q * 4 + 1] = kk.y;
            kv[q * 4 + 2] = kk.z;
            kv[q * 4 + 3] = kk.w;
        }

        #pragma unroll
        for (int rr = 0; rr < 4; ++rr) {
            // LDS row for input row  i + 7 - a, shifted by the -7 halo:
            const int lrow = i0 + rr + (K - 1) - a;          // 0..77, always valid
            const float* xrow = xs + lrow * LWP;
            const int    key  = rowkey(lrow);
            float xw[24];
            #pragma unroll
            for (int q = 0; q < 6; ++q) {
                const float4 xv =
                    *reinterpret_cast<const float4*>(xrow + 4 * (dbase[q] ^ key));
                xw[q * 4 + 0] = xv.x;
                xw[q * 4 + 1] = xv.y;
                xw[q * 4 + 2] = xv.z;
                xw[q * 4 + 3] = xv.w;
            }
            // global col j0+s+7-b  ->  xw[s + 15 - b]
            #pragma unroll
            for (int b = 0; b < K; ++b) {
                #pragma unroll
                for (int s = 0; s < 8; ++s) {
                    acc[rr][s] = fmaf(xw[s + 15 - b], kv[b], acc[rr][s]);
                }
            }
        }
    }

    // ---- write 4x8 tile ----
    float* orow = out + (size_t)n * (P * P) + (size_t)(ibase + i0) * P + j0;
    #pragma unroll
    for (int rr = 0; rr < 4; ++rr) {
        *reinterpret_cast<float4*>(orow + rr * P + 0) =
            make_float4(acc[rr][0], acc[rr][1], acc[rr][2], acc[rr][3]);
        *reinterpret_cast<float4*>(orow + rr * P + 4) =
            make_float4(acc[rr][4], acc[rr][5], acc[rr][6], acc[rr][7]);
    }
}

} // namespace

extern "C" void kernel_launch(void* const* d_in, const int* in_sizes, int n_in,
                              void* d_out, int out_size, void* d_ws, size_t ws_size,
                              hipStream_t stream) {
    const float* patches = (const float*)d_in[0];
    const float* kernels = (const float*)d_in[1];
    float* out = (float*)d_out;

    const int n_images = in_sizes[0] / (P * P);   // 3072
    const int grid = n_images * 2;                // 2 blocks per image

    dwconv_kernel<<<grid, NT, 0, stream>>>(patches, kernels, out);
}

// Round 3
// 490.026 us; speedup vs baseline: 1.2257x; 1.2257x over previous
//
#include <hip/hip_runtime.h>

// Depthwise "true" 2D convolution: 3072 independent 128x128 fp32 images,
// each with its own 15x15 fp32 kernel, same-padding 7.
// y[i,j] = sum_{a,b} x[i+7-a, j+7-b] * k[a,b]   (zero outside [0,128))
//
// R4 -> R5 change: row-major restructure. R3/R4 showed identical
// SQ_LDS_BANK_CONFLICT (1.123e8) under two different swizzles -> the
// ~12.7 cyc/read residual is inherent ds_read_b128 serialization, not a
// fixable conflict. So reduce READ COUNT instead:
//  (1) Walk strip rows t=0..17 once each (was: 60 (a,rr) pairs re-reading
//      18 rows 3.33x). Each row is loaded once into xw and applied to all
//      4 output rows with different kernel rows. x-reads: 360 -> 108.
//  (2) Kernel taps are wave-uniform: read kern[] directly with uniform
//      indices -> compiler scalarizes to s_load, kernel rows live in SGPRs,
//      FMA = v_fmac(v,s,v). Deletes all kernel LDS reads + ks staging.
// Rolling 4-row kernel window, slots rotated statically via 4x-unrolled
// steady-state loop (t=3..14) + explicit head/tail (no runtime-indexed
// register arrays -> no scratch).

namespace {

constexpr int P      = 128;           // patch size
constexpr int K      = 15;            // kernel size
constexpr int HALF   = 64;            // output rows per block
constexpr int LROWS  = HALF + K - 1;  // 78 staged rows
constexpr int LM     = 36;            // logical float4 slots per row (144 floats)
constexpr int LWP    = 160;           // physical row width in floats (40 slots)
constexpr int NT     = 256;

__device__ __forceinline__ int dein(int m) {
    // de-interleave even/odd logical float4 slots
    return (m >> 1) + (m & 1) * 20;
}

__device__ __forceinline__ int rowkey(int row) {
    return (row >> 1) & 6;
}

__global__ __launch_bounds__(NT, 3)
void dwconv_kernel(const float* __restrict__ patches,
                   const float* __restrict__ kernels,
                   float* __restrict__ out)
{
    __shared__ float xs[LROWS * LWP];  // 49920 B input strip

    const int tid   = threadIdx.x;
    const int n     = blockIdx.x >> 1;        // image index 0..3071
    const int halfb = blockIdx.x & 1;
    const int ibase = halfb * HALF;           // first output row of this block

    const float* img  = patches + (size_t)n * (P * P);
    const float* kern = kernels + (size_t)n * (K * K);

    // ---- stage input strip rows [ibase-7, ibase+70] with zero halo ----
    for (int idx = tid; idx < LROWS * LM; idx += NT) {
        const int row = idx / LM;
        const int m   = idx - row * LM;
        const int r   = ibase - 7 + row;       // global input row
        const int g0  = m * 4 - 8;             // global col of first float
        float4 v = make_float4(0.f, 0.f, 0.f, 0.f);
        if ((unsigned)r < (unsigned)P) {
            if (g0 >= 0 && g0 + 3 < P) {
                v = *reinterpret_cast<const float4*>(img + r * P + g0);
            } else {
                float t0 = 0.f, t1 = 0.f, t2 = 0.f, t3 = 0.f;
                const float* rp = img + r * P;
                if ((unsigned)(g0 + 0) < (unsigned)P) t0 = rp[g0 + 0];
                if ((unsigned)(g0 + 1) < (unsigned)P) t1 = rp[g0 + 1];
                if ((unsigned)(g0 + 2) < (unsigned)P) t2 = rp[g0 + 2];
                if ((unsigned)(g0 + 3) < (unsigned)P) t3 = rp[g0 + 3];
                v = make_float4(t0, t1, t2, t3);
            }
        }
        const int phys = dein(m) ^ rowkey(row);
        *reinterpret_cast<float4*>(xs + row * LWP + 4 * phys) = v;
    }
    __syncthreads();

    // ---- per-thread 4x8 output tile, strip-row-major accumulation ----
    const int ty = tid >> 4;       // 0..15
    const int tx = tid & 15;       // 0..15
    const int i0 = ty * 4;         // local output row base (0..60)
    const int j0 = tx * 8;         // output col base (0..120)

    // logical slots per row: m = 2*tx + q -> dein = tx + (q>>1) + (q&1)*20
    const int dbase[6] = { tx + 0, tx + 20, tx + 1, tx + 21, tx + 2, tx + 22 };

    float acc[4][8];
    #pragma unroll
    for (int rr = 0; rr < 4; ++rr)
        #pragma unroll
        for (int s = 0; s < 8; ++s)
            acc[rr][s] = 0.0f;

    float xw[24];        // one strip row window: cols j0-8 .. j0+15
    float kr[4][K];      // rolling kernel rows; slot = a & 3, static indices only

    auto loadx = [&](int t) {
        const int lrow = i0 + t;
        const float* xrow = xs + lrow * LWP;
        const int key = rowkey(lrow);
        #pragma unroll
        for (int q = 0; q < 6; ++q) {
            const float4 xv =
                *reinterpret_cast<const float4*>(xrow + 4 * (dbase[q] ^ key));
            xw[q * 4 + 0] = xv.x;
            xw[q * 4 + 1] = xv.y;
            xw[q * 4 + 2] = xv.z;
            xw[q * 4 + 3] = xv.w;
        }
    };

    // slot is always a compile-time literal at call sites -> static index
    auto loadk = [&](int slot, int a) {
        #pragma unroll
        for (int b = 0; b < K; ++b) kr[slot][b] = kern[a * K + b];
    };

    auto fmarow = [&](int rr, int slot) {
        #pragma unroll
        for (int b = 0; b < K; ++b)
            #pragma unroll
            for (int s = 0; s < 8; ++s)
                acc[rr][s] = fmaf(xw[s + 15 - b], kr[slot][b], acc[rr][s]);
    };

    // head: t = 0,1,2  (kernel rows 14,13,12 -> slots 2,1,0)
    loadk(2, 14); loadk(1, 13); loadk(0, 12);
    loadx(0); fmarow(0, 2);
    loadx(1); fmarow(0, 1); fmarow(1, 2);
    loadx(2); fmarow(0, 0); fmarow(1, 1); fmarow(2, 2);

    // steady state: t = 3..14, all 4 output rows active.
    // a(rr) = rr + 14 - t; tb = 3 (mod 4) makes slot = (rr + 11 - p) & 3 static.
    #pragma unroll 1
    for (int tb = 3; tb <= 14; tb += 4) {
        loadk(3, 14 - tb); loadx(tb + 0);
        fmarow(0, 3); fmarow(1, 0); fmarow(2, 1); fmarow(3, 2);

        loadk(2, 13 - tb); loadx(tb + 1);
        fmarow(0, 2); fmarow(1, 3); fmarow(2, 0); fmarow(3, 1);

        loadk(1, 12 - tb); loadx(tb + 2);
        fmarow(0, 1); fmarow(1, 2); fmarow(2, 3); fmarow(3, 0);

        loadk(0, 11 - tb); loadx(tb + 3);
        fmarow(0, 0); fmarow(1, 1); fmarow(2, 2); fmarow(3, 3);
    }

    // tail: t = 15,16,17 (kernel rows a = rr + 14 - t, all already resident)
    loadx(15); fmarow(1, 0); fmarow(2, 1); fmarow(3, 2);
    loadx(16); fmarow(2, 0); fmarow(3, 1);
    loadx(17); fmarow(3, 0);

    // ---- write 4x8 tile ----
    float* orow = out + (size_t)n * (P * P) + (size_t)(ibase + i0) * P + j0;
    #pragma unroll
    for (int rr = 0; rr < 4; ++rr) {
        *reinterpret_cast<float4*>(orow + rr * P + 0) =
            make_float4(acc[rr][0], acc[rr][1], acc[rr][2], acc[rr][3]);
        *reinterpret_cast<float4*>(orow + rr * P + 4) =
            make_float4(acc[rr][4], acc[rr][5], acc[rr][6], acc[rr][7]);
    }
}

} // namespace

extern "C" void kernel_launch(void* const* d_in, const int* in_sizes, int n_in,
                              void* d_out, int out_size, void* d_ws, size_t ws_size,
                              hipStream_t stream) {
    const float* patches = (const float*)d_in[0];
    const float* kernels = (const float*)d_in[1];
    float* out = (float*)d_out;

    const int n_images = in_sizes[0] / (P * P);   // 3072
    const int grid = n_images * 2;                // 2 blocks per image

    dwconv_kernel<<<grid, NT, 0, stream>>>(patches, kernels, out);
}